// Round 1
// baseline (66.856 us; speedup 1.0000x reference)
//
#include <hip/hip_runtime.h>
#include <math.h>

// Problem geometry (from reference):
//   p3: shape (100,152), stride 8  -> 15200 locs * 3 ars = 45600 anchors
//   p4: shape (50,76),   stride 16 ->  3800 locs * 3 ars = 11400 anchors
//   p5: shape (25,38),   stride 32 ->   950 locs * 3 ars =  2850 anchors
// total anchors = 59850
// outputs flat: boxes[59850*4] | anchors[59850*4] | max_iou[59850]
#define NTOT     59850
#define NPROP    2000
#define ANCH_OFF 239400   // floats
#define MIOU_OFF 478800   // floats
#define PCHUNK   250
#define NCHUNK   8

struct BuildConsts {
    float hw[3][3];   // half-width  [level][aspect]
    float hh[3][3];   // half-height [level][aspect]
    float clampv;     // log(224/8)
};

__global__ __launch_bounds__(256) void build_kernel(
    const float4* __restrict__ d3,
    const float4* __restrict__ d4,
    const float4* __restrict__ d5,
    float* __restrict__ out,
    BuildConsts C)
{
    int g = blockIdx.x * 256 + threadIdx.x;
    if (g >= NTOT) return;

    int level, a, H, s;
    const float4* dl;
    if (g < 45600)      { level = 0; a = g;         H = 100; s = 8;  dl = d3; }
    else if (g < 57000) { level = 1; a = g - 45600; H = 50;  s = 16; dl = d4; }
    else                { level = 2; a = g - 57000; H = 25;  s = 32; dl = d5; }

    int loc = a / 3;
    int r   = a - loc * 3;
    int i   = loc / H;       // runs over W
    int j   = loc - i * H;   // runs over H
    float x = (float)s * ((float)j + 0.5f);
    float y = (float)s * ((float)i + 0.5f);

    float hwv = C.hw[level][r], hhv = C.hh[level][r];
    float ax0 = x - hwv, ay0 = y - hhv;
    float ax1 = x + hwv, ay1 = y + hhv;

    float4 d = dl[a];
    float w  = ax1 - ax0, h = ay1 - ay0;
    float cx = (ax0 + ax1) * 0.5f, cy = (ay0 + ay1) * 0.5f;
    float dwx = fminf(d.z, C.clampv), dwy = fminf(d.w, C.clampv);
    float ncx = cx + w * d.x, ncy = cy + h * d.y;
    float nw  = w * expf(dwx), nh = h * expf(dwy);

    ((float4*)out)[g] = make_float4(ncx - 0.5f * nw, ncy - 0.5f * nh,
                                    ncx + 0.5f * nw, ncy + 0.5f * nh);
    ((float4*)(out + ANCH_OFF))[g] = make_float4(ax0, ay0, ax1, ay1);
    out[MIOU_OFF + g] = 0.0f;   // re-zero every call (replays don't re-poison)
}

// grid (59, 8): x covers 59*1024 anchors (4 per thread), y = proposal chunk
__global__ __launch_bounds__(256) void iou_kernel(
    const float4* __restrict__ props,   // = boxes region (first 2000 rows used)
    const float4* __restrict__ anch,
    float* __restrict__ miou)
{
    __shared__ float4 Pb[PCHUNK];
    __shared__ float  Pa[PCHUNK];

    int tid = threadIdx.x;
    int cy  = blockIdx.y;
    if (tid < PCHUNK) {
        float4 b = props[cy * PCHUNK + tid];
        Pb[tid] = b;
        Pa[tid] = (b.z - b.x) * (b.w - b.y);
    }
    __syncthreads();

    int base = blockIdx.x * 1024 + tid;

    float ax0[4], ay0[4], ax1[4], ay1[4], a2[4], Ib[4], Ub[4];
    bool  valid[4];
    #pragma unroll
    for (int k = 0; k < 4; ++k) {
        int g = base + k * 256;
        valid[k] = (g < NTOT);
        float4 A = anch[valid[k] ? g : 0];
        ax0[k] = A.x; ay0[k] = A.y; ax1[k] = A.z; ay1[k] = A.w;
        a2[k]  = (A.z - A.x) * (A.w - A.y);
        Ib[k]  = 0.0f; Ub[k] = 1.0f;
    }

    #pragma unroll 2
    for (int p = 0; p < PCHUNK; ++p) {
        float4 b  = Pb[p];   // broadcast read, conflict-free
        float  pa = Pa[p];
        #pragma unroll
        for (int k = 0; k < 4; ++k) {
            float xl = fmaxf(b.x, ax0[k]);
            float yl = fmaxf(b.y, ay0[k]);
            float xr = fminf(b.z, ax1[k]);
            float yr = fminf(b.w, ay1[k]);
            float iw = fmaxf(xr - xl, 0.0f);
            float ih = fmaxf(yr - yl, 0.0f);
            float inter = iw * ih;
            float uni   = (pa + a2[k]) - inter;
            // running argmax of inter/uni without dividing: cross-product compare
            bool better = inter * Ub[k] > Ib[k] * uni;
            Ib[k] = better ? inter : Ib[k];
            Ub[k] = better ? uni   : Ub[k];
        }
    }

    #pragma unroll
    for (int k = 0; k < 4; ++k) {
        if (valid[k]) {
            float m = Ib[k] / Ub[k];
            // IoU >= 0, so uint compare == float compare; max is order-independent
            atomicMax((unsigned int*)(miou + base + k * 256), __float_as_uint(m));
        }
    }
}

extern "C" void kernel_launch(void* const* d_in, const int* in_sizes, int n_in,
                              void* d_out, int out_size, void* d_ws, size_t ws_size,
                              hipStream_t stream) {
    // inputs: 0..2 = feats (unused), 3..5 = deltas p3/p4/p5
    const float4* d3 = (const float4*)d_in[3];
    const float4* d4 = (const float4*)d_in[4];
    const float4* d5 = (const float4*)d_in[5];
    float* out = (float*)d_out;

    BuildConsts C;
    const double sArr[3]  = {8.0, 16.0, 32.0};
    const double arArr[3] = {0.5, 1.0, 2.0};
    for (int l = 0; l < 3; ++l) {
        double as   = 4.0 * sArr[l];
        double area = as * as;
        for (int r = 0; r < 3; ++r) {
            double w = sqrt(area / arArr[r]);
            double h = area / w;
            C.hw[l][r] = (float)w * 0.5f;   // matches f32(w) * 0.5 in reference
            C.hh[l][r] = (float)h * 0.5f;
        }
    }
    C.clampv = (float)log(224.0 / 8.0);

    build_kernel<<<dim3((NTOT + 255) / 256), 256, 0, stream>>>(d3, d4, d5, out, C);
    iou_kernel<<<dim3(59, NCHUNK), 256, 0, stream>>>(
        (const float4*)out, (const float4*)(out + ANCH_OFF), out + MIOU_OFF);
}